// Round 1
// baseline (1636.506 us; speedup 1.0000x reference)
//
#include <hip/hip_runtime.h>
#include <cstdint>
#include <cstddef>

// ---------------------------------------------------------------------------
// Qwen3.5 MoE decoder layer, MI355X (gfx950).
// Strategy: split-bf16 (hi+lo) MFMA for the attention chain (router top-2 must
// match the fp32 reference), single-bf16 MFMA for MoE + shared expert.
// ---------------------------------------------------------------------------

#define S_LEN 2048
#define D_MOD 2048
#define N_HEAD 16
#define D_HEAD 128

typedef float f32x4 __attribute__((ext_vector_type(4)));
typedef unsigned short u16x4 __attribute__((ext_vector_type(4)));
typedef __bf16 bf16x8 __attribute__((ext_vector_type(8)));

__device__ __forceinline__ unsigned short f2bf(float f) {
  unsigned u = __builtin_bit_cast(unsigned, f);
  unsigned r = (u + 0x7fffu + ((u >> 16) & 1u)) >> 16;
  return (unsigned short)r;
}
__device__ __forceinline__ float bf2f(unsigned short b) {
  unsigned u = ((unsigned)b) << 16;
  return __builtin_bit_cast(float, u);
}

__device__ __forceinline__ void gl_lds16(const void* g, void* l) {
  __builtin_amdgcn_global_load_lds(
      (const __attribute__((address_space(1))) void*)g,
      (__attribute__((address_space(3))) void*)l, 16, 0, 0);
}

__device__ __forceinline__ float wave_red_sum(float v) {
  #pragma unroll
  for (int o = 32; o; o >>= 1) v += __shfl_down(v, o, 64);
  return v;
}
__device__ __forceinline__ float wave_red_max(float v) {
  #pragma unroll
  for (int o = 32; o; o >>= 1) v = fmaxf(v, __shfl_down(v, o, 64));
  return v;
}

// ------------------------- workspace layout (bytes) -------------------------
static constexpr size_t SZ_SCORES  = (size_t)8 * 2048 * 2048 * 4;   // 134217728
// W2 aliases the scores region (dead by the time MoE weights are needed)
static constexpr size_t O_GUT      = 0;                              // [12288][2048] bf16
static constexpr size_t O_DOWNT    = (size_t)12288 * 2048 * 2;       // [2048][10240] bf16
static constexpr size_t O_SHGUT    = O_DOWNT + (size_t)2048 * 10240 * 2; // [8192][2048]
static constexpr size_t O_W1       = SZ_SCORES;
static constexpr size_t O_QKVGT_H  = O_W1;
static constexpr size_t O_QKVGT_L  = O_QKVGT_H + (size_t)8192 * 2048 * 2;
static constexpr size_t O_WOT_H    = O_QKVGT_L + (size_t)8192 * 2048 * 2;
static constexpr size_t O_WOT_L    = O_WOT_H + (size_t)2048 * 2048 * 2;
static constexpr size_t O3         = O_WOT_L + (size_t)2048 * 2048 * 2;
static constexpr size_t O_XH       = O3;
static constexpr size_t O_XL       = O_XH + (size_t)2048 * 2048 * 2;
static constexpr size_t O_QKVG_H   = O_XL + (size_t)2048 * 2048 * 2;
static constexpr size_t O_QKVG_L   = O_QKVG_H + (size_t)2048 * 8192 * 2;
static constexpr size_t O_GU       = O3;                 // reuse after attention
static constexpr size_t O4         = O_QKVG_L + (size_t)2048 * 8192 * 2;
static constexpr size_t O_VT_H     = O4;
static constexpr size_t O_VT_L     = O_VT_H + (size_t)2048 * 2048 * 2;
static constexpr size_t O_CTX_H    = O_VT_L + (size_t)2048 * 2048 * 2;
static constexpr size_t O_CTX_L    = O_CTX_H + (size_t)2048 * 2048 * 2;
static constexpr size_t O_SHGU     = O4;                 // reuse after attention
static constexpr size_t O_Y        = O_CTX_L + (size_t)2048 * 2048 * 2;
static constexpr size_t O_ROUT     = O_Y + (size_t)2048 * 2048 * 2;

// ------------------------------- GEMM kernel -------------------------------
// C(M,N) = A(M,K) @ B(K,N), with B supplied transposed (Bt[N][K], row-major).
// A addressed in BYTES (lda = row stride in bytes) so fp32-pitch bf16 rows work.
// SPLIT: A and B each have hi/lo bf16 planes; 3 MFMAs per k-step pair.
#define BM 128
#define BN 128
#define BK 64

struct GemmP {
  const char* Ah; const char* Al; long aZ; int lda;   // bytes
  const char* A2; int lda2; int kSplit;               // composite (k>=kSplit)
  const unsigned short* Bh; const unsigned short* Bl; long bZ; int ldb; // elems
  unsigned short* Ch; unsigned short* Cl; long cZ; int ldc;             // elems
  float* Cf; long cfZ; int ldcf;
  const float* bias; long biasZ; int ldbias; float scale;
  const float* res; int ldres;
  int K;
};

// EPI: 0 = split bf16 store, 1 = bf16 store, 2 = f32 scale+bias, 3 = f32 res+acc
template <int EPI, bool SPLIT, bool COMPOSITE>
__global__ __launch_bounds__(256, 2) void gemm_k(GemmP p) {
  __shared__ unsigned short ldsbuf[(SPLIT ? 4 : 2) * BM * BK];
  unsigned short* AhS = ldsbuf;
  unsigned short* BhS = ldsbuf + BM * BK;
  unsigned short* AlS = SPLIT ? ldsbuf + 2 * BM * BK : ldsbuf;
  unsigned short* BlS = SPLIT ? ldsbuf + 3 * BM * BK : ldsbuf;

  const int tid = threadIdx.x;
  const int wid = tid >> 6, lane = tid & 63;
  const int z = blockIdx.z;
  const int m0 = blockIdx.y * BM, n0 = blockIdx.x * BN;

  const char* Ahz = p.Ah + (long)z * p.aZ;
  const char* Alz = SPLIT ? (p.Al + (long)z * p.aZ) : nullptr;
  const unsigned short* Bhz = p.Bh + (long)z * p.bZ;
  const unsigned short* Blz = SPLIT ? (p.Bl + (long)z * p.bZ) : nullptr;

  const int srow = lane >> 3;            // 0..7 within 8-row chunk
  const int skcol = (lane & 7) * 8;      // 0..56 (x8 bf16 = 16B)

  const int wr = wid >> 1, wc = wid & 1;
  const int fm = wr * 64 + (lane & 15);
  const int fn = wc * 64 + (lane & 15);
  const int fk = (lane >> 4) * 8;

  f32x4 acc[4][4];
  #pragma unroll
  for (int i = 0; i < 4; i++)
    #pragma unroll
    for (int j = 0; j < 4; j++) acc[i][j] = f32x4{0.f, 0.f, 0.f, 0.f};

  const int nkt = p.K / BK;
  for (int kt = 0; kt < nkt; ++kt) {
    const int k0 = kt * BK;
    // ---- stage A tile ----
    {
      const char* ab; const char* abl; int ac; long ldax;
      if (COMPOSITE && k0 >= p.kSplit) { ab = p.A2; abl = p.A2; ac = k0 - p.kSplit; ldax = p.lda2; }
      else { ab = Ahz; abl = Alz; ac = k0; ldax = p.lda; }
      #pragma unroll
      for (int i = 0; i < 4; ++i) {
        int ch = (wid << 2) | i;
        int row = (ch << 3) + srow;
        const char* g = ab + (long)(m0 + row) * ldax + (long)(ac + skcol) * 2;
        gl_lds16(g, (void*)(AhS + (ch << 9)));
        if (SPLIT) {
          const char* g2 = abl + (long)(m0 + row) * ldax + (long)(ac + skcol) * 2;
          gl_lds16(g2, (void*)(AlS + (ch << 9)));
        }
      }
    }
    // ---- stage B tile ----
    #pragma unroll
    for (int i = 0; i < 4; ++i) {
      int ch = (wid << 2) | i;
      int row = (ch << 3) + srow;
      const unsigned short* g = Bhz + (long)(n0 + row) * p.ldb + k0 + skcol;
      gl_lds16(g, (void*)(BhS + (ch << 9)));
      if (SPLIT) {
        const unsigned short* g2 = Blz + (long)(n0 + row) * p.ldb + k0 + skcol;
        gl_lds16(g2, (void*)(BlS + (ch << 9)));
      }
    }
    __syncthreads();
    // ---- compute ----
    #pragma unroll
    for (int kk = 0; kk < BK; kk += 32) {
      bf16x8 ah[4], bh[4];
      #pragma unroll
      for (int m = 0; m < 4; ++m)
        ah[m] = *(const bf16x8*)(AhS + (fm + m * 16) * BK + kk + fk);
      #pragma unroll
      for (int n = 0; n < 4; ++n)
        bh[n] = *(const bf16x8*)(BhS + (fn + n * 16) * BK + kk + fk);
      if (SPLIT) {
        bf16x8 al[4], bl[4];
        #pragma unroll
        for (int m = 0; m < 4; ++m)
          al[m] = *(const bf16x8*)(AlS + (fm + m * 16) * BK + kk + fk);
        #pragma unroll
        for (int n = 0; n < 4; ++n)
          bl[n] = *(const bf16x8*)(BlS + (fn + n * 16) * BK + kk + fk);
        #pragma unroll
        for (int m = 0; m < 4; ++m)
          #pragma unroll
          for (int n = 0; n < 4; ++n) {
            acc[m][n] = __builtin_amdgcn_mfma_f32_16x16x32_bf16(ah[m], bh[n], acc[m][n], 0, 0, 0);
            acc[m][n] = __builtin_amdgcn_mfma_f32_16x16x32_bf16(ah[m], bl[n], acc[m][n], 0, 0, 0);
            acc[m][n] = __builtin_amdgcn_mfma_f32_16x16x32_bf16(al[m], bh[n], acc[m][n], 0, 0, 0);
          }
      } else {
        #pragma unroll
        for (int m = 0; m < 4; ++m)
          #pragma unroll
          for (int n = 0; n < 4; ++n)
            acc[m][n] = __builtin_amdgcn_mfma_f32_16x16x32_bf16(ah[m], bh[n], acc[m][n], 0, 0, 0);
      }
    }
    __syncthreads();
  }

  // ---- epilogue ----
  const int r0 = wr * 64 + ((lane >> 4) << 2);
  const int c0 = wc * 64 + (lane & 15);
  #pragma unroll
  for (int m = 0; m < 4; ++m)
    #pragma unroll
    for (int n = 0; n < 4; ++n)
      #pragma unroll
      for (int r = 0; r < 4; ++r) {
        int row = m0 + r0 + m * 16 + r;
        int col = n0 + c0 + n * 16;
        float v = acc[m][n][r];
        if (EPI == 0) {
          long off = (long)z * p.cZ + (long)row * p.ldc + col;
          unsigned short h = f2bf(v);
          p.Ch[off] = h;
          p.Cl[off] = f2bf(v - bf2f(h));
        } else if (EPI == 1) {
          long off = (long)z * p.cZ + (long)row * p.ldc + col;
          p.Ch[off] = f2bf(v);
        } else if (EPI == 2) {
          long off = (long)z * p.cfZ + (long)row * p.ldcf + col;
          p.Cf[off] = v * p.scale + p.bias[(long)z * p.biasZ + (long)row * p.ldbias + col];
        } else {
          long off = (long)row * p.ldcf + col;
          p.Cf[off] = p.res[(long)row * p.ldres + col] + v;
        }
      }
}

// --------------------------- transpose/cast kernel ---------------------------
// src[K][N] (fp32 or bf16) -> dst[N][K] bf16 (optionally split hi/lo planes).
struct TDesc {
  const void* src; long srcOff; int sld; long zsrc;
  unsigned short* dstHi; unsigned short* dstLo; long dstOff; int dld; long zdst;
  int tx, ty, nz, mode;   // mode: 0 f32->split, 1 f32->bf16, 2 bf16->bf16
};
struct TPack { TDesc d[6]; int cum[7]; int nd; };

__global__ __launch_bounds__(256) void trans_k(TPack tp) {
  __shared__ float t[64][65];
  int b = blockIdx.x;
  int di = 0;
  while (di + 1 < tp.nd && b >= tp.cum[di + 1]) di++;
  TDesc d = tp.d[di];
  int rel = b - tp.cum[di];
  int per = d.tx * d.ty;
  int zz = rel / per; rel -= zz * per;
  int tn = rel % d.tx, tk = rel / d.tx;
  int tid = threadIdx.x;
  int rr = tid >> 4, cc = (tid & 15) * 4;
  #pragma unroll
  for (int i = 0; i < 4; i++) {
    int r = rr + i * 16;
    long so = d.srcOff + (long)zz * d.zsrc + (long)(tk * 64 + r) * d.sld + tn * 64 + cc;
    if (d.mode <= 1) {
      f32x4 v = *(const f32x4*)((const float*)d.src + so);
      t[r][cc + 0] = v[0]; t[r][cc + 1] = v[1]; t[r][cc + 2] = v[2]; t[r][cc + 3] = v[3];
    } else {
      u16x4 v = *(const u16x4*)((const unsigned short*)d.src + so);
      t[r][cc + 0] = bf2f(v[0]); t[r][cc + 1] = bf2f(v[1]);
      t[r][cc + 2] = bf2f(v[2]); t[r][cc + 3] = bf2f(v[3]);
    }
  }
  __syncthreads();
  #pragma unroll
  for (int i = 0; i < 4; i++) {
    int n = rr + i * 16;
    int k = cc;
    long off = d.dstOff + (long)zz * d.zdst + (long)(tn * 64 + n) * d.dld + tk * 64 + k;
    u16x4 h, l;
    #pragma unroll
    for (int j = 0; j < 4; j++) {
      float v = t[k + j][n];
      h[j] = f2bf(v);
      l[j] = f2bf(v - bf2f(h[j]));
    }
    *(u16x4*)(d.dstHi + off) = h;
    if (d.mode == 0) *(u16x4*)(d.dstLo + off) = l;
  }
}

// ------------------------------- RMSNorm -------------------------------
__global__ __launch_bounds__(256) void rms_k(const float* __restrict__ in,
                                             const float* __restrict__ w,
                                             unsigned short* oh, unsigned short* ol) {
  int tr = blockIdx.x;
  int tid = threadIdx.x, lane = tid & 63, wid = tid >> 6;
  const float* r = in + (long)tr * D_MOD;
  f32x4 a = ((const f32x4*)r)[tid * 2];
  f32x4 b = ((const f32x4*)r)[tid * 2 + 1];
  float ss = a[0]*a[0] + a[1]*a[1] + a[2]*a[2] + a[3]*a[3]
           + b[0]*b[0] + b[1]*b[1] + b[2]*b[2] + b[3]*b[3];
  ss = wave_red_sum(ss);
  __shared__ float red[4];
  if (lane == 0) red[wid] = ss;
  __syncthreads();
  float sc = 1.0f / sqrtf((red[0] + red[1] + red[2] + red[3]) * (1.0f / 2048.0f) + 1e-6f);
  f32x4 wa = ((const f32x4*)w)[tid * 2];
  f32x4 wb = ((const f32x4*)w)[tid * 2 + 1];
  u16x4 h0, h1, l0, l1;
  #pragma unroll
  for (int j = 0; j < 4; j++) {
    float v0 = a[j] * sc * (1.0f + wa[j]);
    float v1 = b[j] * sc * (1.0f + wb[j]);
    h0[j] = f2bf(v0); l0[j] = f2bf(v0 - bf2f(h0[j]));
    h1[j] = f2bf(v1); l1[j] = f2bf(v1 - bf2f(h1[j]));
  }
  unsigned short* po = oh + (long)tr * D_MOD + tid * 8;
  ((u16x4*)po)[0] = h0; ((u16x4*)po)[1] = h1;
  if (ol) {
    unsigned short* pl = ol + (long)tr * D_MOD + tid * 8;
    ((u16x4*)pl)[0] = l0; ((u16x4*)pl)[1] = l1;
  }
}

// ------------------------------- RoPE (in place on split q,k) ---------------
__global__ __launch_bounds__(256) void rope_k(unsigned short* qh, unsigned short* ql,
                                              const float* __restrict__ cosb,
                                              const float* __restrict__ sinb) {
  int tr = blockIdx.x;
  unsigned short* rh = qh + (long)tr * 8192;
  unsigned short* rl = ql + (long)tr * 8192;
  const float* c = cosb + (long)tr * 128;
  const float* s = sinb + (long)tr * 128;
  for (int i = threadIdx.x; i < 2048; i += 256) {
    int qk = i >> 10;          // 0=q, 1=k
    int rem = i & 1023;
    int hh = rem >> 6, dd = rem & 63;
    int base = qk * 2048 + hh * 128 + dd;
    float a = bf2f(rh[base]) + bf2f(rl[base]);
    float b = bf2f(rh[base + 64]) + bf2f(rl[base + 64]);
    float na = a * c[dd] - b * s[dd];
    float nb = b * c[dd + 64] + a * s[dd + 64];
    unsigned short h;
    h = f2bf(na); rh[base] = h;      rl[base] = f2bf(na - bf2f(h));
    h = f2bf(nb); rh[base + 64] = h; rl[base + 64] = f2bf(nb - bf2f(h));
  }
}

// -------------------- softmax over kv (in-row in-place, f32 -> split bf16) ---
__global__ __launch_bounds__(256) void softmax_k(float* sc) {
  long rowo = ((long)blockIdx.y * 2048 + blockIdx.x) * 2048;
  float* row = sc + rowo;
  int tid = threadIdx.x, lane = tid & 63, wid = tid >> 6;
  f32x4 a = ((const f32x4*)row)[tid * 2];
  f32x4 b = ((const f32x4*)row)[tid * 2 + 1];
  float mx = fmaxf(fmaxf(fmaxf(a[0], a[1]), fmaxf(a[2], a[3])),
                   fmaxf(fmaxf(b[0], b[1]), fmaxf(b[2], b[3])));
  mx = wave_red_max(mx);
  __shared__ float redm[4], reds[4];
  if (lane == 0) redm[wid] = mx;
  __syncthreads();
  mx = fmaxf(fmaxf(redm[0], redm[1]), fmaxf(redm[2], redm[3]));
  float e[8]; float sum = 0.f;
  #pragma unroll
  for (int j = 0; j < 4; j++) { e[j] = __expf(a[j] - mx); sum += e[j]; }
  #pragma unroll
  for (int j = 0; j < 4; j++) { e[4 + j] = __expf(b[j] - mx); sum += e[4 + j]; }
  sum = wave_red_sum(sum);
  if (lane == 0) reds[wid] = sum;
  __syncthreads();
  float inv = 1.0f / (reds[0] + reds[1] + reds[2] + reds[3]);
  unsigned short* ph = (unsigned short*)row;       // bytes [0,4K) of this row
  unsigned short* pl = ph + 2048;                  // bytes [4K,8K)
  u16x4 h0, h1, l0, l1;
  #pragma unroll
  for (int j = 0; j < 4; j++) {
    float p0 = e[j] * inv;     h0[j] = f2bf(p0); l0[j] = f2bf(p0 - bf2f(h0[j]));
    float p1 = e[4 + j] * inv; h1[j] = f2bf(p1); l1[j] = f2bf(p1 - bf2f(h1[j]));
  }
  ((u16x4*)(ph + tid * 8))[0] = h0; ((u16x4*)(ph + tid * 8))[1] = h1;
  ((u16x4*)(pl + tid * 8))[0] = l0; ((u16x4*)(pl + tid * 8))[1] = l1;
}

// ------------------ ctx *= sigmoid(g) (split, in place) ----------------------
__global__ __launch_bounds__(256) void gate_k(unsigned short* ch, unsigned short* cl,
                                              const unsigned short* __restrict__ qh,
                                              const unsigned short* __restrict__ ql) {
  int tr = blockIdx.x;
  long cb = (long)tr * 2048, gb = (long)tr * 8192 + 6144;
  for (int i = threadIdx.x; i < 2048; i += 256) {
    float cv = bf2f(ch[cb + i]) + bf2f(cl[cb + i]);
    float gv = bf2f(qh[gb + i]) + bf2f(ql[gb + i]);
    float v = cv * (1.0f / (1.0f + __expf(-gv)));
    unsigned short h = f2bf(v);
    ch[cb + i] = h;
    cl[cb + i] = f2bf(v - bf2f(h));
  }
}

// ---------------- router: fp32 logits from h (exact selection) ---------------
__global__ __launch_bounds__(256) void router_k(const float* __restrict__ h,
                                                const float* __restrict__ w2,
                                                const float* __restrict__ rw,
                                                const float* __restrict__ sgw,
                                                float* rout) {
  int tr = blockIdx.x;
  const float* r = h + (long)tr * D_MOD;
  int tid = threadIdx.x, lane = tid & 63, wid = tid >> 6;
  float ss = 0.f;
  for (int i = tid; i < 2048; i += 256) { float v = r[i]; ss += v * v; }
  ss = wave_red_sum(ss);
  __shared__ float red[4];
  if (lane == 0) red[wid] = ss;
  __syncthreads();
  float sc = 1.0f / sqrtf((red[0] + red[1] + red[2] + red[3]) * (1.0f / 2048.0f) + 1e-6f);
  float acc[9] = {0, 0, 0, 0, 0, 0, 0, 0, 0};
  for (int i = tid; i < 2048; i += 256) {
    float y = r[i] * sc * (1.0f + w2[i]);
    const float* rr = rw + (long)i * 8;
    #pragma unroll
    for (int e = 0; e < 8; e++) acc[e] += y * rr[e];
    acc[8] += y * sgw[i];
  }
  __shared__ float ared[9][4];
  #pragma unroll
  for (int e = 0; e < 9; e++) {
    float v = wave_red_sum(acc[e]);
    if (lane == 0) ared[e][wid] = v;
  }
  __syncthreads();
  if (tid == 0) {
    float l[9];
    #pragma unroll
    for (int e = 0; e < 9; e++) l[e] = ared[e][0] + ared[e][1] + ared[e][2] + ared[e][3];
    float mx = l[0];
    #pragma unroll
    for (int e = 1; e < 8; e++) mx = fmaxf(mx, l[e]);
    float p[8], sum = 0.f;
    #pragma unroll
    for (int e = 0; e < 8; e++) { p[e] = expf(l[e] - mx); sum += p[e]; }
    #pragma unroll
    for (int e = 0; e < 8; e++) p[e] /= sum;
    int a = 0;
    #pragma unroll
    for (int e = 1; e < 8; e++) if (p[e] > p[a]) a = e;
    int b = (a == 0) ? 1 : 0;
    #pragma unroll
    for (int e = 0; e < 8; e++) if (e != a && p[e] > p[b]) b = e;
    float den = p[a] + p[b];
    float* o = rout + (long)tr * 8;
    o[0] = (float)a; o[1] = (float)b;
    o[2] = p[a] / den; o[3] = p[b] / den;
    o[4] = 1.0f / (1.0f + expf(-l[8]));
  }
}

// ------- act = silu(g)*u * (routing weight | sigmoid gate), in place ---------
__global__ __launch_bounds__(256) void act_scale_k(unsigned short* gu, unsigned short* shgu,
                                                   const float* __restrict__ rout) {
  int tr = blockIdx.x;
  int k0 = blockIdx.y * 2048 + threadIdx.x * 8;
  const float* o = rout + (long)tr * 8;
  int e0 = (int)o[0], e1 = (int)o[1];
  float w;
  unsigned short *gp, *up, *dst;
  if (k0 < 6144) {
    int e = k0 / 768;
    w = (e == e0) ? o[2] : (e == e1) ? o[3] : 0.0f;
    gp = gu + (long)tr * 12288 + k0;
    up = gp + 6144;
    dst = gp;
  } else {
    int j = k0 - 6144;
    w = o[4];
    gp = shgu + (long)tr * 8192 + j;
    up = gp + 4096;
    dst = gp;
  }
  u16x4 g0 = ((const u16x4*)gp)[0], g1 = ((const u16x4*)gp)[1];
  u16x4 u0 = ((const u16x4*)up)[0], u1 = ((const u16x4*)up)[1];
  u16x4 r0, r1;
  #pragma unroll
  for (int j = 0; j < 4; j++) {
    float g = bf2f(g0[j]), u = bf2f(u0[j]);
    r0[j] = f2bf(g / (1.0f + __expf(-g)) * u * w);
    float g2 = bf2f(g1[j]), u2 = bf2f(u1[j]);
    r1[j] = f2bf(g2 / (1.0f + __expf(-g2)) * u2 * w);
  }
  ((u16x4*)dst)[0] = r0; ((u16x4*)dst)[1] = r1;
}

// --------------------------------- launch -----------------------------------
extern "C" void kernel_launch(void* const* d_in, const int* in_sizes, int n_in,
                              void* d_out, int out_size, void* d_ws, size_t ws_size,
                              hipStream_t stream) {
  const float* hidden = (const float*)d_in[0];
  const float* abias  = (const float*)d_in[1];
  const float* cosb   = (const float*)d_in[2];
  const float* sinb   = (const float*)d_in[3];
  const float* ln1    = (const float*)d_in[4];
  const float* ln2    = (const float*)d_in[5];
  const float* wq     = (const float*)d_in[6];
  const float* wk     = (const float*)d_in[7];
  const float* wv     = (const float*)d_in[8];
  const float* wg     = (const float*)d_in[9];
  const float* wo     = (const float*)d_in[10];
  const float* rw     = (const float*)d_in[11];
  const float* eg     = (const float*)d_in[12];
  const float* eu     = (const float*)d_in[13];
  const float* ed     = (const float*)d_in[14];
  const float* shg    = (const float*)d_in[15];
  const float* shu    = (const float*)d_in[16];
  const float* shd    = (const float*)d_in[17];
  const float* sgw    = (const float*)d_in[18];

  char* ws = (char*)d_ws;
  float* scores = (float*)(ws + 0);
  unsigned short* guT    = (unsigned short*)(ws + O_GUT);
  unsigned short* downT  = (unsigned short*)(ws + O_DOWNT);
  unsigned short* shguT  = (unsigned short*)(ws + O_SHGUT);
  unsigned short* qkvgT_h = (unsigned short*)(ws + O_QKVGT_H);
  unsigned short* qkvgT_l = (unsigned short*)(ws + O_QKVGT_L);
  unsigned short* woT_h  = (unsigned short*)(ws + O_WOT_H);
  unsigned short* woT_l  = (unsigned short*)(ws + O_WOT_L);
  unsigned short* xh     = (unsigned short*)(ws + O_XH);
  unsigned short* xl     = (unsigned short*)(ws + O_XL);
  unsigned short* qkvg_h = (unsigned short*)(ws + O_QKVG_H);
  unsigned short* qkvg_l = (unsigned short*)(ws + O_QKVG_L);
  unsigned short* gu_act = (unsigned short*)(ws + O_GU);
  unsigned short* vT_h   = (unsigned short*)(ws + O_VT_H);
  unsigned short* vT_l   = (unsigned short*)(ws + O_VT_L);
  unsigned short* ctx_h  = (unsigned short*)(ws + O_CTX_H);
  unsigned short* ctx_l  = (unsigned short*)(ws + O_CTX_L);
  unsigned short* shgu_a = (unsigned short*)(ws + O_SHGU);
  unsigned short* ybuf   = (unsigned short*)(ws + O_Y);
  float* rout            = (float*)(ws + O_ROUT);

  // 1) transpose pass 1: wq/wk/wv/wg -> qkvgT (split), wo -> woT (split)
  {
    TPack t{};
    const float* srcs[5] = {wq, wk, wv, wg, wo};
    for (int i = 0; i < 5; i++) {
      TDesc& d = t.d[i];
      d.src = srcs[i]; d.srcOff = 0; d.sld = 2048; d.zsrc = 0;
      if (i < 4) { d.dstHi = qkvgT_h; d.dstLo = qkvgT_l; d.dstOff = (long)i * 2048 * 2048; }
      else       { d.dstHi = woT_h;   d.dstLo = woT_l;   d.dstOff = 0; }
      d.dld = 2048; d.zdst = 0; d.tx = 32; d.ty = 32; d.nz = 1; d.mode = 0;
      t.cum[i] = i * 1024;
    }
    t.cum[5] = 5120; t.nd = 5;
    hipLaunchKernelGGL(trans_k, dim3(5120), dim3(256), 0, stream, t);
  }
  // 2) x = rmsnorm(hidden, ln1) -> split
  hipLaunchKernelGGL(rms_k, dim3(2048), dim3(256), 0, stream, hidden, ln1, xh, xl);
  // 3) qkvg = x @ [wq|wk|wv|wg]   (split in/out)
  {
    GemmP g{};
    g.Ah = (const char*)xh; g.Al = (const char*)xl; g.aZ = 0; g.lda = 4096;
    g.Bh = qkvgT_h; g.Bl = qkvgT_l; g.bZ = 0; g.ldb = 2048;
    g.Ch = qkvg_h; g.Cl = qkvg_l; g.cZ = 0; g.ldc = 8192;
    g.K = 2048;
    hipLaunchKernelGGL((gemm_k<0, true, false>), dim3(64, 16, 1), dim3(256), 0, stream, g);
  }
  // 4) RoPE on q,k
  hipLaunchKernelGGL(rope_k, dim3(2048), dim3(256), 0, stream, qkvg_h, qkvg_l, cosb, sinb);
  // 5) transpose v -> vT (both planes via nz=2)
  {
    TPack t{};
    TDesc& d = t.d[0];
    d.src = qkvg_h; d.srcOff = 4096; d.sld = 8192;
    d.zsrc = (long)(O_QKVG_L - O_QKVG_H) / 2;
    d.dstHi = vT_h; d.dstLo = nullptr; d.dstOff = 0; d.dld = 2048;
    d.zdst = (long)(O_VT_L - O_VT_H) / 2;
    d.tx = 32; d.ty = 32; d.nz = 2; d.mode = 2;
    t.cum[0] = 0; t.cum[1] = 2048; t.nd = 1;
    hipLaunchKernelGGL(trans_k, dim3(2048), dim3(256), 0, stream, t);
  }
  // 6-11) attention in two 8-head chunks
  for (int c = 0; c < 2; c++) {
    {  // scores = q @ k^T / sqrt(dh) + bias   (split in, fp32 out)
      GemmP g{};
      g.Ah = (const char*)qkvg_h + (long)c * 8 * 256;
      g.Al = (const char*)qkvg_l + (long)c * 8 * 256;
      g.aZ = 256; g.lda = 16384;
      g.Bh = qkvg_h + 2048 + (long)c * 8 * 128;
      g.Bl = qkvg_l + 2048 + (long)c * 8 * 128;
      g.bZ = 128; g.ldb = 8192;
      g.Cf = scores; g.cfZ = (long)2048 * 2048; g.ldcf = 2048;
      g.bias = abias; g.biasZ = 0; g.ldbias = 2048;
      g.scale = 0.08838834764831845f;
      g.K = 128;
      hipLaunchKernelGGL((gemm_k<2, true, false>), dim3(16, 16, 8), dim3(256), 0, stream, g);
    }
    hipLaunchKernelGGL(softmax_k, dim3(2048, 8), dim3(256), 0, stream, scores);
    {  // ctx = P @ V  (P split planes inside score rows, Vt split)
      GemmP g{};
      g.Ah = (const char*)scores; g.Al = (const char*)scores + 4096;
      g.aZ = (long)2048 * 8192; g.lda = 8192;
      g.Bh = vT_h + (long)c * 8 * 128 * 2048;
      g.Bl = vT_l + (long)c * 8 * 128 * 2048;
      g.bZ = (long)128 * 2048; g.ldb = 2048;
      g.Ch = ctx_h + (long)c * 8 * 128;
      g.Cl = ctx_l + (long)c * 8 * 128;
      g.cZ = 128; g.ldc = 2048;
      g.K = 2048;
      hipLaunchKernelGGL((gemm_k<0, true, false>), dim3(1, 16, 8), dim3(256), 0, stream, g);
    }
  }
  // 12) ctx *= sigmoid(g)
  hipLaunchKernelGGL(gate_k, dim3(2048), dim3(256), 0, stream, ctx_h, ctx_l, qkvg_h, qkvg_l);
  // 13) h = hidden + ctx @ wo   -> d_out (fp32)
  {
    GemmP g{};
    g.Ah = (const char*)ctx_h; g.Al = (const char*)ctx_l; g.aZ = 0; g.lda = 4096;
    g.Bh = woT_h; g.Bl = woT_l; g.bZ = 0; g.ldb = 2048;
    g.Cf = (float*)d_out; g.cfZ = 0; g.ldcf = 2048;
    g.res = hidden; g.ldres = 2048;
    g.K = 2048;
    hipLaunchKernelGGL((gemm_k<3, true, false>), dim3(16, 16, 1), dim3(256), 0, stream, g);
  }
  // 14) y = rmsnorm(h, ln2) -> single bf16
  hipLaunchKernelGGL(rms_k, dim3(2048), dim3(256), 0, stream, (const float*)d_out, ln2, ybuf,
                     (unsigned short*)nullptr);
  // 15) router (fp32 logits straight from h)
  hipLaunchKernelGGL(router_k, dim3(2048), dim3(256), 0, stream, (const float*)d_out, ln2, rw,
                     sgw, rout);
  // 16) transpose pass 2 (MoE + shared weights, single bf16) into scores region
  {
    TPack t{};
    t.d[0] = {eg, 0, 768, (long)2048 * 768, guT, nullptr, 0, 2048, (long)768 * 2048, 12, 32, 8, 1};
    t.d[1] = {eu, 0, 768, (long)2048 * 768, guT, nullptr, (long)6144 * 2048, 2048, (long)768 * 2048, 12, 32, 8, 1};
    t.d[2] = {ed, 0, 2048, (long)768 * 2048, downT, nullptr, 0, 10240, 768, 32, 12, 8, 1};
    t.d[3] = {shd, 0, 2048, 0, downT, nullptr, 6144, 10240, 0, 32, 64, 1, 1};
    t.d[4] = {shg, 0, 4096, 0, shguT, nullptr, 0, 2048, 0, 64, 32, 1, 1};
    t.d[5] = {shu, 0, 4096, 0, shguT, nullptr, (long)4096 * 2048, 2048, 0, 64, 32, 1, 1};
    t.cum[0] = 0; t.cum[1] = 3072; t.cum[2] = 6144; t.cum[3] = 9216;
    t.cum[4] = 11264; t.cum[5] = 13312; t.cum[6] = 15360; t.nd = 6;
    hipLaunchKernelGGL(trans_k, dim3(15360), dim3(256), 0, stream, t);
  }
  // 17) gu = y @ [gate|up] for all experts  (N = 12288)
  {
    GemmP g{};
    g.Ah = (const char*)ybuf; g.aZ = 0; g.lda = 4096;
    g.Bh = guT; g.bZ = 0; g.ldb = 2048;
    g.Ch = gu_act; g.cZ = 0; g.ldc = 12288;
    g.K = 2048;
    hipLaunchKernelGGL((gemm_k<1, false, false>), dim3(96, 16, 1), dim3(256), 0, stream, g);
  }
  // 18) shgu = y @ [sh_gate|sh_up]  (N = 8192)
  {
    GemmP g{};
    g.Ah = (const char*)ybuf; g.aZ = 0; g.lda = 4096;
    g.Bh = shguT; g.bZ = 0; g.ldb = 2048;
    g.Ch = shgu_a; g.cZ = 0; g.ldc = 8192;
    g.K = 2048;
    hipLaunchKernelGGL((gemm_k<1, false, false>), dim3(64, 16, 1), dim3(256), 0, stream, g);
  }
  // 19) act = silu(g)*u * (routing weight | sigmoid), in place
  hipLaunchKernelGGL(act_scale_k, dim3(2048, 5), dim3(256), 0, stream, gu_act, shgu_a, rout);
  // 20) out = h + act @ [exp_down ; sh_down]   (composite A, K = 10240)
  {
    GemmP g{};
    g.Ah = (const char*)gu_act; g.aZ = 0; g.lda = 24576;
    g.A2 = (const char*)shgu_a; g.lda2 = 16384; g.kSplit = 6144;
    g.Bh = downT; g.bZ = 0; g.ldb = 10240;
    g.Cf = (float*)d_out; g.cfZ = 0; g.ldcf = 2048;
    g.res = (const float*)d_out; g.ldres = 2048;
    g.K = 10240;
    hipLaunchKernelGGL((gemm_k<3, false, true>), dim3(16, 16, 1), dim3(256), 0, stream, g);
  }
}